// Round 2
// baseline (755.525 us; speedup 1.0000x reference)
//
#include <hip/hip_runtime.h>
#include <hip/hip_bf16.h>
#include <stdint.h>

#define DD 32   // input dim
#define HH 64   // hidden dim
#define LOG2E 1.44269504088896340736f

typedef float f32x4 __attribute__((ext_vector_type(4)));
typedef short s16x8 __attribute__((ext_vector_type(8)));

__device__ __forceinline__ uint32_t pk2(float lo, float hi) {
  __hip_bfloat162 t = __float22bfloat162_rn(make_float2(lo, hi));
  union { __hip_bfloat162 b; uint32_t u; } v; v.b = t;
  return v.u;
}

__global__ __launch_bounds__(512, 2)
void lstm_fused(const float* __restrict__ x,
                const float* __restrict__ W_ih,
                const float* __restrict__ W_hh,
                const float* __restrict__ b_ih,
                const float* __restrict__ b_hh,
                const float* __restrict__ fc_W,
                const float* __restrict__ fc_b,
                float* __restrict__ out,
                int T)
{
  const int tid  = threadIdx.x;
  const int wv   = tid >> 6;     // wave 0..7
  const int g    = wv & 3;       // gate-column group (16 h-cols)
  const int rh   = wv >> 2;      // duplication pair: which r's we update
  const int lane = tid & 63;
  const int lr   = lane & 15;    // A-row (batch) / D-col index
  const int lq   = lane >> 4;    // k-group 0..3
  const int bm   = blockIdx.x * 16;

  __shared__ __align__(16) uint16_t hbuf[2][16 * 64]; // bf16 h, double buffered, XOR-swizzled

  // ---- persistent weights as B fragments, pre-scaled by log2e (2*log2e for g-gate) ----
  const int h0 = 16 * g + lr;
  s16x8 Bx[4], Bh0[4], Bh1[4];
  f32x4 biasv[4];
  #pragma unroll
  for (int j = 0; j < 4; ++j) {
    const int n = 64 * j + h0;
    const float sc = (j == 2) ? (2.0f * LOG2E) : LOG2E;
    {
      const float* p = W_ih + n * DD + lq * 8;
      f32x4 a = *(const f32x4*)p;
      f32x4 b = *(const f32x4*)(p + 4);
      union { uint32_t u[4]; s16x8 s; } pk;
      pk.u[0] = pk2(a[0]*sc, a[1]*sc); pk.u[1] = pk2(a[2]*sc, a[3]*sc);
      pk.u[2] = pk2(b[0]*sc, b[1]*sc); pk.u[3] = pk2(b[2]*sc, b[3]*sc);
      Bx[j] = pk.s;
    }
    {
      const float* p = W_hh + n * HH + lq * 8;
      f32x4 a = *(const f32x4*)p;
      f32x4 b = *(const f32x4*)(p + 4);
      union { uint32_t u[4]; s16x8 s; } pk;
      pk.u[0] = pk2(a[0]*sc, a[1]*sc); pk.u[1] = pk2(a[2]*sc, a[3]*sc);
      pk.u[2] = pk2(b[0]*sc, b[1]*sc); pk.u[3] = pk2(b[2]*sc, b[3]*sc);
      Bh0[j] = pk.s;
    }
    {
      const float* p = W_hh + n * HH + 32 + lq * 8;
      f32x4 a = *(const f32x4*)p;
      f32x4 b = *(const f32x4*)(p + 4);
      union { uint32_t u[4]; s16x8 s; } pk;
      pk.u[0] = pk2(a[0]*sc, a[1]*sc); pk.u[1] = pk2(a[2]*sc, a[3]*sc);
      pk.u[2] = pk2(b[0]*sc, b[1]*sc); pk.u[3] = pk2(b[2]*sc, b[3]*sc);
      Bh1[j] = pk.s;
    }
    const float bb = (b_ih[n] + b_hh[n]) * sc;
    biasv[j] = (f32x4){bb, bb, bb, bb};
  }

  for (int i = tid; i < 16 * 64; i += 512) hbuf[0][i] = 0;

  float c[2] = {0.f, 0.f};

  const float* xbase = x + (size_t)(bm + lr) * (size_t)T * DD + lq * 8;
  f32x4 xa = *(const f32x4*)xbase;
  f32x4 xb = *(const f32x4*)(xbase + 4);

  __syncthreads();

  const f32x4 zz = {0.f, 0.f, 0.f, 0.f};
  const int sw = lr & 7;

  auto step = [&](int t, const uint16_t* __restrict__ hr, uint16_t* __restrict__ hw) {
    union { uint32_t u[4]; s16x8 s; } ax;
    ax.u[0] = pk2(xa[0], xa[1]); ax.u[1] = pk2(xa[2], xa[3]);
    ax.u[2] = pk2(xb[0], xb[1]); ax.u[3] = pk2(xb[2], xb[3]);
    {
      const size_t off = (size_t)((t + 1 < T) ? (t + 1) : t) * DD;
      xa = *(const f32x4*)(xbase + off);
      xb = *(const f32x4*)(xbase + off + 4);
    }
    f32x4 acc[4], acc2[4];
    #pragma unroll
    for (int j = 0; j < 4; ++j)
      acc[j] = __builtin_amdgcn_mfma_f32_16x16x32_bf16(ax.s, Bx[j], biasv[j], 0, 0, 0);

    __syncthreads();  // prev step's h writes visible

    s16x8 ah0 = *(const s16x8*)(hr + lr * 64 + (((lq    ) ^ sw) << 3));
    s16x8 ah1 = *(const s16x8*)(hr + lr * 64 + (((lq + 4) ^ sw) << 3));
    #pragma unroll
    for (int j = 0; j < 4; ++j)
      acc[j]  = __builtin_amdgcn_mfma_f32_16x16x32_bf16(ah0, Bh0[j], acc[j], 0, 0, 0);
    #pragma unroll
    for (int j = 0; j < 4; ++j)
      acc2[j] = __builtin_amdgcn_mfma_f32_16x16x32_bf16(ah1, Bh1[j], zz, 0, 0, 0);

    // cell update for this wave's 2 accumulator rows (compile-time R: no dyn vec idx)
    #define CELL(R, CI) {                                                         \
      float gi = acc[0][R] + acc2[0][R];                                          \
      float gf = acc[1][R] + acc2[1][R];                                          \
      float gg = acc[2][R] + acc2[2][R];                                          \
      float go = acc[3][R] + acc2[3][R];                                          \
      float ig = __builtin_amdgcn_rcpf(1.f + __builtin_amdgcn_exp2f(-gi));        \
      float fg = __builtin_amdgcn_rcpf(1.f + __builtin_amdgcn_exp2f(-gf));        \
      float gt = 1.f - 2.f * __builtin_amdgcn_rcpf(1.f + __builtin_amdgcn_exp2f(gg)); \
      float og = __builtin_amdgcn_rcpf(1.f + __builtin_amdgcn_exp2f(-go));        \
      c[CI] = fg * c[CI] + ig * gt;                                               \
      float tc = 1.f - 2.f * __builtin_amdgcn_rcpf(                               \
                   1.f + __builtin_amdgcn_exp2f((2.0f * LOG2E) * c[CI]));         \
      float hv = og * tc;                                                         \
      const int m = 4 * lq + (R);                                                 \
      __hip_bfloat16 hb = __float2bfloat16(hv);                                   \
      union { __hip_bfloat16 b; uint16_t u; } cv; cv.b = hb;                      \
      hw[m * 64 + ((((h0 >> 3) ^ (m & 7))) << 3) + (h0 & 7)] = cv.u; }

    if (rh == 0) { CELL(0, 0) CELL(1, 1) } else { CELL(2, 0) CELL(3, 1) }
    #undef CELL
    // next step's pre-barrier work is register-only; its __syncthreads orders
    // these writes before the reads of hw's buffer.
  };

  for (int t = 0; t < T; t += 2) {
    step(t,     hbuf[0], hbuf[1]);
    step(t + 1, hbuf[1], hbuf[0]);
  }

  __syncthreads();  // final h (bf16) in hbuf[0]

  // ---- epilogue: logits = h_last @ fc_W^T + fc_b ----
  if (tid < 160) {
    const int m = tid / 10, cl = tid % 10;
    float s = fc_b[cl];
    const float* wr = fc_W + cl * HH;
    #pragma unroll
    for (int k = 0; k < HH; ++k) {
      union { uint32_t u; float f; } v;
      v.u = (uint32_t)hbuf[0][m * 64 + (((k >> 3) ^ (m & 7)) << 3) + (k & 7)] << 16;
      s += v.f * wr[k];
    }
    out[(size_t)(bm + m) * 10 + cl] = s;
  }
}

extern "C" void kernel_launch(void* const* d_in, const int* in_sizes, int n_in,
                              void* d_out, int out_size, void* d_ws, size_t ws_size,
                              hipStream_t stream) {
  const float* x    = (const float*)d_in[0];
  const float* W_ih = (const float*)d_in[1];
  const float* W_hh = (const float*)d_in[2];
  const float* b_ih = (const float*)d_in[3];
  const float* b_hh = (const float*)d_in[4];
  const float* fc_W = (const float*)d_in[5];
  const float* fc_b = (const float*)d_in[6];
  float* out = (float*)d_out;

  const int B = out_size / 10;            // 2048
  const int T = in_sizes[0] / (B * DD);   // 1024

  dim3 grid(B / 16), block(512);
  hipLaunchKernelGGL(lstm_fused, grid, block, 0, stream,
                     x, W_ih, W_hh, b_ih, b_hh, fc_W, fc_b, out, T);
}

// Round 3
// 554.113 us; speedup vs baseline: 1.3635x; 1.3635x over previous
//
#include <hip/hip_runtime.h>
#include <hip/hip_bf16.h>
#include <stdint.h>

#define DD 32   // input dim
#define HH 64   // hidden dim
#define LOG2E 1.44269504088896340736f

typedef float f32x4 __attribute__((ext_vector_type(4)));
typedef short s16x8 __attribute__((ext_vector_type(8)));

__device__ __forceinline__ uint32_t pk2(float lo, float hi) {
  __hip_bfloat162 t = __float22bfloat162_rn(make_float2(lo, hi));
  union { __hip_bfloat162 b; uint32_t u; } v; v.b = t;
  return v.u;
}
__device__ __forceinline__ uint16_t f2bf(float f) {
  __hip_bfloat16 hb = __float2bfloat16(f);
  union { __hip_bfloat16 b; uint16_t u; } cv; cv.b = hb;
  return cv.u;
}

// Relaxed workgroup barrier: order LDS ops only; do NOT drain vmcnt, so the
// x-prefetch global loads stay in flight across timestep boundaries (T4).
#define BAR() asm volatile("s_waitcnt lgkmcnt(0)\n\ts_barrier" ::: "memory")

__global__ __launch_bounds__(256, 1)
void lstm_fused(const float* __restrict__ x,
                const float* __restrict__ W_ih,
                const float* __restrict__ W_hh,
                const float* __restrict__ b_ih,
                const float* __restrict__ b_hh,
                const float* __restrict__ fc_W,
                const float* __restrict__ fc_b,
                float* __restrict__ out,
                int T)
{
  const int tid  = threadIdx.x;
  const int g    = tid >> 6;     // wave 0..3 -> 16-column group
  const int lane = tid & 63;
  const int lr   = lane & 15;    // batch row within A / D col index
  const int lq   = lane >> 4;    // k-group 0..3
  const int bm   = blockIdx.x * 16;

  __shared__ __align__(16) uint16_t hbuf[2][16 * 64]; // bf16 h, dbuf, XOR-swizzled

  // ---- persistent weights as B fragments, pre-scaled by log2e (2*log2e for g-gate) ----
  const int h0 = 16 * g + lr;
  s16x8 Bx[4], Bh0[4], Bh1[4];
  f32x4 biasv[4];
  #pragma unroll
  for (int j = 0; j < 4; ++j) {
    const int n = 64 * j + h0;
    const float sc = (j == 2) ? (2.0f * LOG2E) : LOG2E;
    {
      const float* p = W_ih + n * DD + lq * 8;
      f32x4 a = *(const f32x4*)p;
      f32x4 b = *(const f32x4*)(p + 4);
      union { uint32_t u[4]; s16x8 s; } pk;
      pk.u[0] = pk2(a[0]*sc, a[1]*sc); pk.u[1] = pk2(a[2]*sc, a[3]*sc);
      pk.u[2] = pk2(b[0]*sc, b[1]*sc); pk.u[3] = pk2(b[2]*sc, b[3]*sc);
      Bx[j] = pk.s;
    }
    {
      const float* p = W_hh + n * HH + lq * 8;
      f32x4 a = *(const f32x4*)p;
      f32x4 b = *(const f32x4*)(p + 4);
      union { uint32_t u[4]; s16x8 s; } pk;
      pk.u[0] = pk2(a[0]*sc, a[1]*sc); pk.u[1] = pk2(a[2]*sc, a[3]*sc);
      pk.u[2] = pk2(b[0]*sc, b[1]*sc); pk.u[3] = pk2(b[2]*sc, b[3]*sc);
      Bh0[j] = pk.s;
    }
    {
      const float* p = W_hh + n * HH + 32 + lq * 8;
      f32x4 a = *(const f32x4*)p;
      f32x4 b = *(const f32x4*)(p + 4);
      union { uint32_t u[4]; s16x8 s; } pk;
      pk.u[0] = pk2(a[0]*sc, a[1]*sc); pk.u[1] = pk2(a[2]*sc, a[3]*sc);
      pk.u[2] = pk2(b[0]*sc, b[1]*sc); pk.u[3] = pk2(b[2]*sc, b[3]*sc);
      Bh1[j] = pk.s;
    }
    const float bb = (b_ih[n] + b_hh[n]) * sc;
    biasv[j] = (f32x4){bb, bb, bb, bb};
  }

  for (int i = tid; i < 16 * 64; i += 256) hbuf[0][i] = 0;

  float c[4] = {0.f, 0.f, 0.f, 0.f};

  // 2-deep x prefetch: (xa0,xb0) feeds even steps, (xa1,xb1) odd steps.
  const float* xbase = x + (size_t)(bm + lr) * (size_t)T * DD + lq * 8;
  f32x4 xa0 = *(const f32x4*)xbase;
  f32x4 xb0 = *(const f32x4*)(xbase + 4);
  f32x4 xa1 = *(const f32x4*)(xbase + DD);
  f32x4 xb1 = *(const f32x4*)(xbase + DD + 4);

  __syncthreads();

  const int sw = lr & 7;

  auto step = [&](f32x4& xa, f32x4& xb, int tpre,
                  const uint16_t* __restrict__ hr, uint16_t* __restrict__ hw) {
    // pack current x (prefetched 2 steps ago) into A fragment
    union { uint32_t u[4]; s16x8 s; } ax;
    ax.u[0] = pk2(xa[0], xa[1]); ax.u[1] = pk2(xa[2], xa[3]);
    ax.u[2] = pk2(xb[0], xb[1]); ax.u[3] = pk2(xb[2], xb[3]);
    // x-part MFMAs (h-independent; overlaps other waves' tail of prev step)
    f32x4 acc[4];
    #pragma unroll
    for (int j = 0; j < 4; ++j)
      acc[j] = __builtin_amdgcn_mfma_f32_16x16x32_bf16(ax.s, Bx[j], biasv[j], 0, 0, 0);

    BAR();  // lgkmcnt-only: prev step's h writes visible, x loads stay in flight

    // issue prefetch for t+2 — ~1.7 steps of slack before its pack
    {
      const size_t off = (size_t)tpre * DD;
      xa = *(const f32x4*)(xbase + off);
      xb = *(const f32x4*)(xbase + off + 4);
    }

    s16x8 ah0 = *(const s16x8*)(hr + lr * 64 + (((lq    ) ^ sw) << 3));
    s16x8 ah1 = *(const s16x8*)(hr + lr * 64 + (((lq + 4) ^ sw) << 3));
    #pragma unroll
    for (int j = 0; j < 4; ++j)
      acc[j] = __builtin_amdgcn_mfma_f32_16x16x32_bf16(ah0, Bh0[j], acc[j], 0, 0, 0);
    #pragma unroll
    for (int j = 0; j < 4; ++j)
      acc[j] = __builtin_amdgcn_mfma_f32_16x16x32_bf16(ah1, Bh1[j], acc[j], 0, 0, 0);

    // LSTM cell update; lane owns cells (m = 4*lq+r, h0). Weights pre-scaled
    // by log2e so sigmoid/tanh are pure exp2/rcp chains.
    #define CELL(R) {                                                               \
      float ig = __builtin_amdgcn_rcpf(1.f + __builtin_amdgcn_exp2f(-acc[0][R]));   \
      float fg = __builtin_amdgcn_rcpf(1.f + __builtin_amdgcn_exp2f(-acc[1][R]));   \
      float gt = 1.f - 2.f * __builtin_amdgcn_rcpf(1.f + __builtin_amdgcn_exp2f(acc[2][R])); \
      float og = __builtin_amdgcn_rcpf(1.f + __builtin_amdgcn_exp2f(-acc[3][R]));   \
      c[R] = fg * c[R] + ig * gt;                                                   \
      float tc = 1.f - 2.f * __builtin_amdgcn_rcpf(                                 \
                   1.f + __builtin_amdgcn_exp2f((2.0f * LOG2E) * c[R]));            \
      float hv = og * tc;                                                           \
      const int m = 4 * lq + (R);                                                   \
      hw[m * 64 + ((((h0 >> 3) ^ (m & 7))) << 3) + (h0 & 7)] = f2bf(hv); }
    CELL(0) CELL(1) CELL(2) CELL(3)
    #undef CELL
    // next step's pre-barrier work is register-only; its BAR orders these
    // writes before any wave reads hw's buffer.
  };

  for (int t = 0; t < T; t += 2) {
    int p0 = (t + 2 < T) ? (t + 2) : (T - 1);
    int p1 = (t + 3 < T) ? (t + 3) : (T - 1);
    step(xa0, xb0, p0, hbuf[0], hbuf[1]);
    step(xa1, xb1, p1, hbuf[1], hbuf[0]);
  }

  __syncthreads();  // final h (bf16) in hbuf[0]

  // ---- epilogue: logits = h_last @ fc_W^T + fc_b ----
  if (tid < 160) {
    const int m = tid / 10, cl = tid % 10;
    float s = fc_b[cl];
    const float* wr = fc_W + cl * HH;
    #pragma unroll
    for (int k = 0; k < HH; ++k) {
      union { uint32_t u; float f; } v;
      v.u = (uint32_t)hbuf[0][m * 64 + (((k >> 3) ^ (m & 7)) << 3) + (k & 7)] << 16;
      s += v.f * wr[k];
    }
    out[(size_t)(bm + m) * 10 + cl] = s;
  }
}

extern "C" void kernel_launch(void* const* d_in, const int* in_sizes, int n_in,
                              void* d_out, int out_size, void* d_ws, size_t ws_size,
                              hipStream_t stream) {
  const float* x    = (const float*)d_in[0];
  const float* W_ih = (const float*)d_in[1];
  const float* W_hh = (const float*)d_in[2];
  const float* b_ih = (const float*)d_in[3];
  const float* b_hh = (const float*)d_in[4];
  const float* fc_W = (const float*)d_in[5];
  const float* fc_b = (const float*)d_in[6];
  float* out = (float*)d_out;

  const int B = out_size / 10;            // 2048
  const int T = in_sizes[0] / (B * DD);   // 1024

  dim3 grid(B / 16), block(256);
  hipLaunchKernelGGL(lstm_fused, grid, block, 0, stream,
                     x, W_ih, W_hh, b_ih, b_hh, fc_W, fc_b, out, T);
}